// Round 4
// baseline (333.227 us; speedup 1.0000x reference)
//
#include <hip/hip_runtime.h>

// RoIPooling: img (1,512,512,256) f32, rois (1,256,4) i32 (x,y,w,h), w=h=28 fixed.
// out (1,256,7,7,256) f32: out[r,p,q,c] = max_{i,j in 0..3} img[0, x+4p+i, y+4q+j, c]
//
// Memory-bound gather: ~205 MB read + 12.8 MB write -> ~35 us floor @ 6.3 TB/s.
// One wave per (r,p,q) output position, 4 positions (waves) per 256-thread block:
//  - lane l owns channels 4l..4l+3 as float4 -> each pixel load = one coalesced
//    1024 B transaction (64 lanes x 16 B contiguous).
//  - all 16 window loads issued into a static-indexed reg array before the max
//    tree -> 16 loads in flight per wave (MLP), no per-load vmcnt serialization.
//  - 256-thread blocks lift the 1-wave-per-workgroup residency cap (~16 wg/CU)
//    -> up to 2x resident waves vs the 64-thread version.

#define CH4   64      // 256 channels / 4 per float4 == one float4 per lane
#define IMW   512
#define NPOS  49      // 7*7 output positions per ROI

__global__ __launch_bounds__(256) void
roipool_kernel(const float* __restrict__ img,
               const int*   __restrict__ rois,
               float*       __restrict__ out) {
    const int g    = blockIdx.x * 4 + (threadIdx.x >> 6);  // global (r,p,q) id
    const int lane = threadIdx.x & 63;

    const int r  = g / NPOS;
    const int pq = g - r * NPOS;
    const int p  = pq / 7;
    const int q  = pq - p * 7;

    // Wave-uniform ROI coords -> scalar loads.
    const int x = rois[r * 4 + 0];       // row offset (dim 1)
    const int y = rois[r * 4 + 1];       // col offset (dim 2)

    const float4* src = reinterpret_cast<const float4*>(img)
                      + ((size_t)(x + p * 4) * IMW + (y + q * 4)) * CH4 + lane;

    // Issue all 16 loads (static indexing -> registers, not scratch).
    float4 v[16];
#pragma unroll
    for (int i = 0; i < 4; ++i) {
#pragma unroll
        for (int j = 0; j < 4; ++j) {
            v[i * 4 + j] = src[(size_t)(i * IMW + j) * CH4];
        }
    }

    float4 m = v[0];
#pragma unroll
    for (int k = 1; k < 16; ++k) {
        m.x = fmaxf(m.x, v[k].x);
        m.y = fmaxf(m.y, v[k].y);
        m.z = fmaxf(m.z, v[k].z);
        m.w = fmaxf(m.w, v[k].w);
    }

    reinterpret_cast<float4*>(out)[(size_t)g * CH4 + lane] = m;
}

extern "C" void kernel_launch(void* const* d_in, const int* in_sizes, int n_in,
                              void* d_out, int out_size, void* d_ws, size_t ws_size,
                              hipStream_t stream) {
    const float* img  = (const float*)d_in[0];   // (1,512,512,256) f32
    const int*   rois = (const int*)  d_in[1];   // (1,256,4) i32
    float*       out  = (float*)d_out;           // (1,256,7,7,256) f32

    const int R    = in_sizes[1] / 4;            // 256
    const int grid = (R * NPOS) / 4;             // 4 positions (waves) per block
    roipool_kernel<<<grid, 256, 0, stream>>>(img, rois, out);
}